// Round 2
// baseline (174.507 us; speedup 1.0000x reference)
//
#include <hip/hip_runtime.h>
#include <hip/hip_bf16.h>
#include <math.h>

#define S_LEN 2048
#define E_DIM 1024
#define NHEAD 8
#define DHEAD 128
#define MEPS 1e-6f
#define LNEPS 1e-5f

typedef __bf16 bf16x8 __attribute__((ext_vector_type(8)));
typedef float f32x4 __attribute__((ext_vector_type(4)));

// split x (f32) into hi+lo bf16 with hi = rn(x), lo = rn(x - hi)
__device__ inline void split8(const float* x, bf16x8& hi, bf16x8& lo) {
#pragma unroll
  for (int e = 0; e < 8; ++e) {
    float v = x[e];
    __bf16 h = (__bf16)v;
    hi[e] = h;
    lo[e] = (__bf16)(v - (float)h);
  }
}

// ------------- kernel 1: gate projections ig/fg = [q,k,v] @ W^T + b -------------
__global__ __launch_bounds__(256) void gates_kernel(
    const float* __restrict__ q, const float* __restrict__ k, const float* __restrict__ v,
    const float* __restrict__ igw, const float* __restrict__ igb,
    const float* __restrict__ fgw, const float* __restrict__ fgb,
    float* __restrict__ ig, float* __restrict__ fg) {
  int s = blockIdx.x;
  int t = threadIdx.x;
  float acc[16];
#pragma unroll
  for (int i = 0; i < 16; ++i) acc[i] = 0.f;
  for (int ii = 0; ii < 12; ++ii) {
    int idx = ii * 256 + t;
    float xv;
    if (idx < 1024) xv = q[s * 1024 + idx];
    else if (idx < 2048) xv = k[s * 1024 + (idx - 1024)];
    else xv = v[s * 1024 + (idx - 2048)];
#pragma unroll
    for (int h = 0; h < 8; ++h) {
      acc[h]     = fmaf(xv, igw[h * 3072 + idx], acc[h]);
      acc[8 + h] = fmaf(xv, fgw[h * 3072 + idx], acc[8 + h]);
    }
  }
#pragma unroll
  for (int i = 0; i < 16; ++i) {
    float a = acc[i];
    a += __shfl_xor(a, 1); a += __shfl_xor(a, 2); a += __shfl_xor(a, 4);
    a += __shfl_xor(a, 8); a += __shfl_xor(a, 16); a += __shfl_xor(a, 32);
    acc[i] = a;
  }
  __shared__ float red[4][16];
  int wave = t >> 6, lane = t & 63;
  if (lane == 0) {
#pragma unroll
    for (int i = 0; i < 16; ++i) red[wave][i] = acc[i];
  }
  __syncthreads();
  if (t < 16) {
    float sres = red[0][t] + red[1][t] + red[2][t] + red[3][t];
    int h = t & 7;
    if (t < 8) ig[h * S_LEN + s] = sres + igb[h];
    else       fg[h * S_LEN + s] = sres + fgb[h];
  }
}

// ------------- kernel 2 (f64): cs=cumsum(logsig(fg)); g=ig-cs; M=prefmax(g); rexp=exp(-(cs+M)) -------------
__global__ void scan_kernel(const float* __restrict__ ig, const float* __restrict__ fg,
                            double* __restrict__ g, double* __restrict__ Mv,
                            float* __restrict__ rexpv) {
  int h = blockIdx.x;
  int lane = threadIdx.x;  // 64 threads
  double cs0[32];
  const float* fgp = fg + h * S_LEN + lane * 32;
  double run = 0.0;
#pragma unroll
  for (int e = 0; e < 32; ++e) {
    double x = (double)fgp[e];
    double ls = fmin(x, 0.0) - log1p(exp(-fabs(x)));
    run += ls;
    cs0[e] = run;
  }
  double incl = run;
#pragma unroll
  for (int off = 1; off < 64; off <<= 1) {
    double nb = __shfl_up(incl, off);
    if (lane >= off) incl += nb;
  }
  double base = __shfl_up(incl, 1);
  if (lane == 0) base = 0.0;
#pragma unroll
  for (int e = 0; e < 32; ++e) cs0[e] += base;

  const float* igp = ig + h * S_LEN + lane * 32;
  double gv[32];
#pragma unroll
  for (int e = 0; e < 32; ++e) {
    gv[e] = (double)igp[e] - cs0[e];
    g[h * S_LEN + lane * 32 + e] = gv[e];
  }
  double pm = -INFINITY;
#pragma unroll
  for (int e = 0; e < 32; ++e) {
    pm = fmax(pm, gv[e]);
    gv[e] = pm;   // in-lane prefix max
  }
  double inclm = pm;
#pragma unroll
  for (int off = 1; off < 64; off <<= 1) {
    double nb = __shfl_up(inclm, off);
    if (lane >= off) inclm = fmax(inclm, nb);
  }
  double basem = __shfl_up(inclm, 1);
  if (lane == 0) basem = -INFINITY;
#pragma unroll
  for (int e = 0; e < 32; ++e) {
    double Mi = fmax(basem, gv[e]);
    Mv[h * S_LEN + lane * 32 + e] = Mi;
    rexpv[h * S_LEN + lane * 32 + e] = (float)exp(-(cs0[e] + Mi));
  }
}

// ------------- kernel 3: flash-style causal weighted attention (split-bf16 MFMA) -------------
__global__ __launch_bounds__(256) void attn_kernel(
    const float* __restrict__ q, const float* __restrict__ k, const float* __restrict__ v,
    const double* __restrict__ g, const double* __restrict__ Mv,
    const float* __restrict__ rexpv, float* __restrict__ out) {
  int h  = blockIdx.x >> 5;   // 8 heads
  int qb = blockIdx.x & 31;   // 32 query blocks of 64
  int tid = threadIdx.x;
  int wave = tid >> 6, lane = tid & 63;
  int lhalf = lane >> 4;      // 0..3
  int l15 = lane & 15;

  __shared__ __bf16 KtH[64 * 128], KtL[64 * 128];   // [kv row][d], swizzled
  __shared__ __bf16 VtH[128 * 64], VtL[128 * 64];   // [d][kv row] transposed, swizzled
  __shared__ __bf16 PbH[4][16 * 64], PbL[4][16 * 64];

  int r0 = qb * 64 + wave * 16;
  const float scale = 0.08838834764831845f;  // 1/sqrt(128)

  // Q fragments hi/lo: lane holds Q[r0 + l15][kc*32 + lhalf*8 + e]
  bf16x8 qfh[4], qfl[4];
  {
    const float* qp = q + (r0 + l15) * E_DIM + h * DHEAD + lhalf * 8;
#pragma unroll
    for (int kc = 0; kc < 4; ++kc) {
      float buf[8];
      *(float4*)&buf[0] = *(const float4*)(qp + kc * 32);
      *(float4*)&buf[4] = *(const float4*)(qp + kc * 32 + 4);
      split8(buf, qfh[kc], qfl[kc]);
    }
  }
  // per-row constants (rows r0 + lhalf*4 + rg)
  double Mreg[4];
  float rexp[4];
#pragma unroll
  for (int rg = 0; rg < 4; ++rg) {
    int i = r0 + lhalf * 4 + rg;
    Mreg[rg] = Mv[h * S_LEN + i];
    rexp[rg] = rexpv[h * S_LEN + i];
  }

  f32x4 acc[8];
#pragma unroll
  for (int nt = 0; nt < 8; ++nt) acc[nt] = (f32x4){0.f, 0.f, 0.f, 0.f};
  float bacc[4] = {0.f, 0.f, 0.f, 0.f};

  char* PwH = (char*)&PbH[wave][0];
  char* PwL = (char*)&PbL[wave][0];

  for (int kb = 0; kb <= qb; ++kb) {
    int kvbase = kb * 64;
    __syncthreads();   // previous iter's LDS reads done
    // ---- stage K [64][128] fp32 -> bf16 hi/lo, swizzled ----
    {
      int rr = tid >> 4;
      int c0 = (tid & 15) * 8;
#pragma unroll
      for (int it = 0; it < 4; ++it) {
        int r = rr + it * 16;
        const float* kp = k + (kvbase + r) * E_DIM + h * DHEAD + c0;
        float buf[8];
        *(float4*)&buf[0] = *(const float4*)kp;
        *(float4*)&buf[4] = *(const float4*)(kp + 4);
        bf16x8 fh, fl;
        split8(buf, fh, fl);
        int off = (r * 256 + c0 * 2) ^ ((r & 7) << 4);
        *(bf16x8*)((char*)KtH + off) = fh;
        *(bf16x8*)((char*)KtL + off) = fl;
      }
      // ---- stage V transposed [128][64] hi/lo ----
      int c = tid & 127;          // d index
      int rb = (tid >> 7) * 8;    // 0 or 8
#pragma unroll
      for (int it = 0; it < 4; ++it) {
        int rbase = rb + it * 16;
        float buf[8];
#pragma unroll
        for (int e = 0; e < 8; ++e)
          buf[e] = v[(kvbase + rbase + e) * E_DIM + h * DHEAD + c];
        bf16x8 fh, fl;
        split8(buf, fh, fl);
        int off = (c * 128 + rbase * 2) ^ ((c & 7) << 4);
        *(bf16x8*)((char*)VtH + off) = fh;
        *(bf16x8*)((char*)VtL + off) = fl;
      }
    }
    __syncthreads();
    // ---- QK^T (16x64 per wave), split product, weights, P hi/lo store ----
#pragma unroll
    for (int ct = 0; ct < 4; ++ct) {
      f32x4 cacc = (f32x4){0.f, 0.f, 0.f, 0.f};
#pragma unroll
      for (int kc = 0; kc < 4; ++kc) {
        int krow = ct * 16 + l15;
        int off = (krow * 256 + (kc * 32 + lhalf * 8) * 2) ^ ((krow & 7) << 4);
        bf16x8 kh = *(const bf16x8*)((const char*)KtH + off);
        bf16x8 kl = *(const bf16x8*)((const char*)KtL + off);
        cacc = __builtin_amdgcn_mfma_f32_16x16x32_bf16(qfh[kc], kh, cacc, 0, 0, 0);
        cacc = __builtin_amdgcn_mfma_f32_16x16x32_bf16(qfh[kc], kl, cacc, 0, 0, 0);
        cacc = __builtin_amdgcn_mfma_f32_16x16x32_bf16(qfl[kc], kh, cacc, 0, 0, 0);
      }
      int j = kvbase + ct * 16 + l15;
      double gj = g[h * S_LEN + j];
#pragma unroll
      for (int rg = 0; rg < 4; ++rg) {
        int i = r0 + lhalf * 4 + rg;
        float pv = 0.f;
        if (j <= i) pv = cacc[rg] * scale * __expf((float)(gj - Mreg[rg]));
        bacc[rg] += pv;
        __bf16 ph = (__bf16)pv;
        __bf16 pl = (__bf16)(pv - (float)ph);
        int prow = lhalf * 4 + rg;
        int pcol = ct * 16 + l15;
        int poff = (prow * 128 + pcol * 2) ^ ((prow & 7) << 4);
        *(__bf16*)(PwH + poff) = ph;
        *(__bf16*)(PwL + poff) = pl;
      }
    }
    __syncthreads();
    // ---- PV: [16x64] @ [64x128], split product ----
#pragma unroll
    for (int kc2 = 0; kc2 < 2; ++kc2) {
      int poff = (l15 * 128 + (kc2 * 32 + lhalf * 8) * 2) ^ ((l15 & 7) << 4);
      bf16x8 pfh = *(const bf16x8*)(PwH + poff);
      bf16x8 pfl = *(const bf16x8*)(PwL + poff);
#pragma unroll
      for (int nt = 0; nt < 8; ++nt) {
        int vrow = nt * 16 + l15;
        int voff = (vrow * 128 + (kc2 * 32 + lhalf * 8) * 2) ^ ((vrow & 7) << 4);
        bf16x8 vfh = *(const bf16x8*)((const char*)VtH + voff);
        bf16x8 vfl = *(const bf16x8*)((const char*)VtL + voff);
        acc[nt] = __builtin_amdgcn_mfma_f32_16x16x32_bf16(pfh, vfh, acc[nt], 0, 0, 0);
        acc[nt] = __builtin_amdgcn_mfma_f32_16x16x32_bf16(pfh, vfl, acc[nt], 0, 0, 0);
        acc[nt] = __builtin_amdgcn_mfma_f32_16x16x32_bf16(pfl, vfh, acc[nt], 0, 0, 0);
      }
    }
  }

  // ---- epilogue: reduce b over the 16 cols, normalize, store ----
  float invn[4];
#pragma unroll
  for (int rg = 0; rg < 4; ++rg) {
    float b = bacc[rg];
    b += __shfl_xor(b, 1); b += __shfl_xor(b, 2);
    b += __shfl_xor(b, 4); b += __shfl_xor(b, 8);
    float norm = fmaxf(fabsf(b), rexp[rg]) + MEPS;
    invn[rg] = 1.f / norm;
  }
#pragma unroll
  for (int nt = 0; nt < 8; ++nt) {
#pragma unroll
    for (int rg = 0; rg < 4; ++rg) {
      int i = r0 + lhalf * 4 + rg;
      out[i * E_DIM + h * DHEAD + nt * 16 + l15] = acc[nt][rg] * invn[rg];
    }
  }
}

// ------------- kernel 4: in-place LayerNorm over E -------------
__global__ __launch_bounds__(256) void ln_kernel(float* __restrict__ io, const float* __restrict__ lnw) {
  int s = blockIdx.x, t = threadIdx.x;
  float4 x = *(const float4*)(io + s * E_DIM + t * 4);
  float sum = x.x + x.y + x.z + x.w;
  float sq  = x.x * x.x + x.y * x.y + x.z * x.z + x.w * x.w;
#pragma unroll
  for (int off = 1; off < 64; off <<= 1) {
    sum += __shfl_xor(sum, off);
    sq  += __shfl_xor(sq, off);
  }
  __shared__ float ps[4][2];
  int wave = t >> 6;
  if ((t & 63) == 0) { ps[wave][0] = sum; ps[wave][1] = sq; }
  __syncthreads();
  float ts = ps[0][0] + ps[1][0] + ps[2][0] + ps[3][0];
  float tq = ps[0][1] + ps[1][1] + ps[2][1] + ps[3][1];
  float mu = ts * (1.f / E_DIM);
  float var = tq * (1.f / E_DIM) - mu * mu;
  float inv = rsqrtf(var + LNEPS);
  float4 w = *(const float4*)(lnw + t * 4);
  float4 o;
  o.x = (x.x - mu) * inv * w.x;
  o.y = (x.y - mu) * inv * w.y;
  o.z = (x.z - mu) * inv * w.z;
  o.w = (x.w - mu) * inv * w.w;
  *(float4*)(io + s * E_DIM + t * 4) = o;
}

extern "C" void kernel_launch(void* const* d_in, const int* in_sizes, int n_in,
                              void* d_out, int out_size, void* d_ws, size_t ws_size,
                              hipStream_t stream) {
  const float* q   = (const float*)d_in[0];
  const float* k   = (const float*)d_in[1];
  const float* v   = (const float*)d_in[2];
  const float* igw = (const float*)d_in[3];
  const float* igb = (const float*)d_in[4];
  const float* fgw = (const float*)d_in[5];
  const float* fgb = (const float*)d_in[6];
  const float* lnw = (const float*)d_in[7];
  float* out = (float*)d_out;

  float*  ig    = (float*)d_ws;                              // [NH][S] f32
  float*  fg    = ig + NHEAD * S_LEN;                        // [NH][S] f32
  double* g64   = (double*)((char*)d_ws + 128 * 1024);       // [NH][S] f64
  double* M64   = g64 + NHEAD * S_LEN;                       // [NH][S] f64
  float*  rexpv = (float*)(M64 + NHEAD * S_LEN);             // [NH][S] f32

  gates_kernel<<<dim3(S_LEN), dim3(256), 0, stream>>>(q, k, v, igw, igb, fgw, fgb, ig, fg);
  scan_kernel<<<dim3(NHEAD), dim3(64), 0, stream>>>(ig, fg, g64, M64, rexpv);
  attn_kernel<<<dim3(NHEAD * 32), dim3(256), 0, stream>>>(q, k, v, g64, M64, rexpv, out);
  ln_kernel<<<dim3(S_LEN), dim3(256), 0, stream>>>(out, lnw);
}